// Round 3
// baseline (3107.175 us; speedup 1.0000x reference)
//
#include <hip/hip_runtime.h>
#include <hip/hip_bf16.h>
#include <math.h>

// GCN forward: 4 GraphConv layers + sum-pool + FC head + softmax.
// N_NODES=100000, N_EDGES=3200000, N_GRAPHS=64, IN=128, DIM=32.
//
// Round-3 structure:
//  - Segmented counting sort of edges into 256-dst-node tile buckets
//    (no global atomics; per-(chunk,bucket) regions are block-exclusive,
//    so stores become full-line writebacks -> kills round-2's 16x write amp).
//  - Aggregation: one block per dst tile; B-tile in LDS (+1-col pad),
//    float4 row gathers (8 lanes/edge, 8 edges/wave-instr), ds_add_f32.

#define TILE_NODES 256           // dst nodes per bucket/tile
#define CE 25600                 // edges per sort chunk
#define SCAN_CHUNK 2048
#define MAX_NB 1024              // LDS sizing bound (N <= 262144)

// ---------------- Pass 1: per-chunk histogram over dst tiles ----------------
__global__ __launch_bounds__(1024) void k_hist2(
    const int* __restrict__ dst, int* __restrict__ histT,
    int n_edges, int NB, int C)
{
    __shared__ int hist[MAX_NB];
    const int c = blockIdx.x;
    for (int b = threadIdx.x; b < NB; b += 1024) hist[b] = 0;
    __syncthreads();
    const int beg = c * CE;
    const int end = min(beg + CE, n_edges);
    for (int e = beg + threadIdx.x; e < end; e += 1024)
        atomicAdd(&hist[dst[e] >> 8], 1);
    __syncthreads();
    for (int b = threadIdx.x; b < NB; b += 1024)
        histT[b * C + c] = hist[b];
}

// ---------------- Pass 2: hierarchical exclusive scan of histT ----------------
__global__ __launch_bounds__(256) void k_chunk_sum(
    const int* __restrict__ v, int* __restrict__ part, int n)
{
    __shared__ int red[256];
    const int base = blockIdx.x * SCAN_CHUNK;
    int s = 0;
    for (int i = threadIdx.x; i < SCAN_CHUNK; i += 256) {
        int idx = base + i;
        if (idx < n) s += v[idx];
    }
    red[threadIdx.x] = s;
    __syncthreads();
    for (int off = 128; off > 0; off >>= 1) {
        if (threadIdx.x < off) red[threadIdx.x] += red[threadIdx.x + off];
        __syncthreads();
    }
    if (threadIdx.x == 0) part[blockIdx.x] = red[0];
}

__global__ void k_scan_part(int* __restrict__ part, int nparts)
{
    if (threadIdx.x == 0 && blockIdx.x == 0) {
        int run = 0;
        for (int i = 0; i < nparts; ++i) { int v = part[i]; part[i] = run; run += v; }
    }
}

__global__ __launch_bounds__(256) void k_write_off(
    const int* __restrict__ v, const int* __restrict__ part,
    int* __restrict__ off, int n, int total)
{
    __shared__ int lds[256];
    const int tid   = threadIdx.x;
    const int base  = blockIdx.x * SCAN_CHUNK;
    const int tbase = base + tid * 8;
    int c[8];
    int tot = 0;
#pragma unroll
    for (int m = 0; m < 8; ++m) {
        int idx = tbase + m;
        c[m] = (idx < n) ? v[idx] : 0;
        tot += c[m];
    }
    lds[tid] = tot;
    __syncthreads();
    for (int o = 1; o < 256; o <<= 1) {
        int val = (tid >= o) ? lds[tid - o] : 0;
        __syncthreads();
        lds[tid] += val;
        __syncthreads();
    }
    int run = part[blockIdx.x] + lds[tid] - tot;
#pragma unroll
    for (int m = 0; m < 8; ++m) {
        int idx = tbase + m;
        if (idx < n) off[idx] = run;
        run += c[m];
    }
    if (blockIdx.x == 0 && tid == 0) off[n] = total;
}

// ---------------- Pass 3: place packed edges at block-exclusive offsets ----------------
__global__ __launch_bounds__(1024) void k_binfill(
    const int* __restrict__ src, const int* __restrict__ dst,
    const int* __restrict__ off, unsigned int* __restrict__ ebuf,
    int n_edges, int NB, int C)
{
    __shared__ int lcur[MAX_NB];
    const int c = blockIdx.x;
    for (int b = threadIdx.x; b < NB; b += 1024)
        lcur[b] = off[b * C + c];
    __syncthreads();
    const int beg = c * CE;
    const int end = min(beg + CE, n_edges);
    for (int e = beg + threadIdx.x; e < end; e += 1024) {
        const int d = dst[e];
        const int b = d >> 8;
        const unsigned int dl = (unsigned int)(d & 255);
        const int pos = atomicAdd(&lcur[b], 1);
        ebuf[pos] = (dl << 17) | (unsigned int)src[e];
    }
}

// ---------------- Layer 0: A = x@Wn0 ; B = x@Ws0 + bn0 ----------------
__global__ __launch_bounds__(256) void k_layer0(
    const float* __restrict__ x, const float* __restrict__ Wn0,
    const float* __restrict__ bn0, const float* __restrict__ Ws0,
    float* __restrict__ A, float* __restrict__ B, int n_nodes)
{
    __shared__ float sWn[128 * 32];
    __shared__ float sWs[128 * 32];
    __shared__ float sx[32 * 128];

    for (int i = threadIdx.x; i < 128 * 32; i += 256) {
        sWn[i] = Wn0[i];
        sWs[i] = Ws0[i];
    }
    const int tile = blockIdx.x * 32;
    {
        const float4* s4 = (const float4*)(x + (size_t)tile * 128);
        const int lim = (n_nodes - tile) * 32;
#pragma unroll
        for (int m = 0; m < 4; ++m) {
            int i = threadIdx.x + m * 256;
            if (i < lim) ((float4*)sx)[i] = s4[i];
        }
    }
    const int j = threadIdx.x & 31;
    const int r = threadIdx.x >> 5;
    const float bias = bn0[j];
    __syncthreads();

    float accA[4] = {0.f, 0.f, 0.f, 0.f};
    float accB[4] = {bias, bias, bias, bias};
#pragma unroll 8
    for (int k = 0; k < 128; ++k) {
        const float wn = sWn[k * 32 + j];
        const float ws = sWs[k * 32 + j];
#pragma unroll
        for (int m = 0; m < 4; ++m) {
            const float xv = sx[(r + 8 * m) * 128 + k];
            accA[m] += xv * wn;
            accB[m] += xv * ws;
        }
    }
#pragma unroll
    for (int m = 0; m < 4; ++m) {
        const int node = tile + r + 8 * m;
        if (node < n_nodes) {
            A[(size_t)node * 32 + j] = accA[m];
            B[(size_t)node * 32 + j] = accB[m];
        }
    }
}

// ------------- Layers 1..3: A = relu(H)@Wn ; B = relu(H)@Ws + bn -------------
__global__ __launch_bounds__(256) void k_layer(
    const float* __restrict__ Hpre, const float* __restrict__ Wn,
    const float* __restrict__ bnv, const float* __restrict__ Ws,
    float* __restrict__ A, float* __restrict__ B, int n_nodes)
{
    __shared__ float sWn[32 * 32];
    __shared__ float sWs[32 * 32];
    __shared__ float sh[64 * 32];

    for (int i = threadIdx.x; i < 1024; i += 256) {
        sWn[i] = Wn[i];
        sWs[i] = Ws[i];
    }
    const int tile = blockIdx.x * 64;
    {
        const float4* s4 = (const float4*)(Hpre + (size_t)tile * 32);
        const int lim = (n_nodes - tile) * 8;
#pragma unroll
        for (int m = 0; m < 2; ++m) {
            int i = threadIdx.x + m * 256;
            if (i < lim) {
                float4 v = s4[i];
                v.x = fmaxf(v.x, 0.f); v.y = fmaxf(v.y, 0.f);
                v.z = fmaxf(v.z, 0.f); v.w = fmaxf(v.w, 0.f);
                ((float4*)sh)[i] = v;
            }
        }
    }
    const int j = threadIdx.x & 31;
    const int r = threadIdx.x >> 5;
    const float bias = bnv[j];
    __syncthreads();

    float accA[8] = {0.f};
    float accB[8];
#pragma unroll
    for (int m = 0; m < 8; ++m) accB[m] = bias;
#pragma unroll
    for (int k = 0; k < 32; ++k) {
        const float wn = sWn[k * 32 + j];
        const float ws = sWs[k * 32 + j];
#pragma unroll
        for (int m = 0; m < 8; ++m) {
            const float hv = sh[(r + 8 * m) * 32 + k];
            accA[m] += hv * wn;
            accB[m] += hv * ws;
        }
    }
#pragma unroll
    for (int m = 0; m < 8; ++m) {
        const int node = tile + r + 8 * m;
        if (node < n_nodes) {
            A[(size_t)node * 32 + j] = accA[m];
            B[(size_t)node * 32 + j] = accB[m];
        }
    }
}

// ------------- Aggregation: per dst-tile block, B-tile in LDS -------------
// ebuf entry: (dl<<17)|src.  8 lanes/edge (float4 each), 8 edges per wave-instr.
__global__ __launch_bounds__(1024) void k_agg(
    const int* __restrict__ off, const unsigned int* __restrict__ ebuf,
    const float* __restrict__ A, float* __restrict__ B,
    int n_nodes, int NB, int C, int n_edges)
{
    __shared__ float sB[TILE_NODES * 33];   // +1-col pad to spread ds_add banks
    const int b = blockIdx.x;
    const int node_base = b * TILE_NODES;
    const int n_valid = min(TILE_NODES, n_nodes - node_base);
    const int tid = threadIdx.x;

    // init tile with B (self + bias), computed by the layer kernel
    for (int i = tid; i < n_valid * 32; i += 1024)
        sB[(i >> 5) * 33 + (i & 31)] = B[(size_t)node_base * 32 + i];
    __syncthreads();

    const int beg = off[b * C];
    const int end = (b + 1 < NB) ? off[(b + 1) * C] : n_edges;

    const int wv   = tid >> 6;          // wave id (16 waves)
    const int l    = tid & 63;
    const int sub  = l >> 3;            // 0..7: which edge in the 8-pack
    const int quad = l & 7;             // which float4 of the 32-float row
    const float4* __restrict__ A4 = (const float4*)A;

    for (int e0 = beg + wv * 8; e0 < end; e0 += 16 * 8) {
        const int e = e0 + sub;
        if (e < end) {
            const unsigned int v = ebuf[e];
            const int s  = (int)(v & 0x1FFFFu);
            const int dl = (int)(v >> 17);
            const float4 a = A4[(size_t)s * 8 + quad];
            float* rowp = &sB[dl * 33 + quad * 4];
            atomicAdd(rowp + 0, a.x);
            atomicAdd(rowp + 1, a.y);
            atomicAdd(rowp + 2, a.z);
            atomicAdd(rowp + 3, a.w);
        }
    }
    __syncthreads();
    for (int i = tid; i < n_valid * 32; i += 1024)
        B[(size_t)node_base * 32 + i] = sB[(i >> 5) * 33 + (i & 31)];
}

// ---------------- Per-graph sum pool ----------------
__global__ __launch_bounds__(256) void k_pool(
    const float* __restrict__ H, const int* __restrict__ gids,
    float* __restrict__ hg, int n_nodes)
{
    const int g = blockIdx.x;
    int lo = 0, hi = n_nodes;
    while (lo < hi) { int m = (lo + hi) >> 1; if (gids[m] < g) lo = m + 1; else hi = m; }
    const int start = lo;
    hi = n_nodes;
    while (lo < hi) { int m = (lo + hi) >> 1; if (gids[m] < g + 1) lo = m + 1; else hi = m; }
    const int end = lo;

    const int j = threadIdx.x & 31;
    const int s = threadIdx.x >> 5;
    float acc = 0.f;
    for (int n = start + s; n < end; n += 8)
        acc += fmaxf(H[(size_t)n * 32 + j], 0.f);

    __shared__ float red[256];
    red[threadIdx.x] = acc;
    __syncthreads();
    if (s == 0) {
        float t = 0.f;
#pragma unroll
        for (int k = 0; k < 8; ++k) t += red[k * 32 + j];
        hg[g * 32 + j] = t;
    }
}

// ---------------- FC head + softmax ----------------
__global__ __launch_bounds__(64) void k_head(
    const float* __restrict__ hg,
    const float* __restrict__ Wfc1, const float* __restrict__ bfc1,
    const float* __restrict__ Wout, const float* __restrict__ bout,
    float* __restrict__ out, int n_graphs)
{
    const int g = blockIdx.x * blockDim.x + threadIdx.x;
    if (g >= n_graphs) return;
    float h[32];
#pragma unroll
    for (int k = 0; k < 32; ++k) h[k] = hg[g * 32 + k];
    float z[8];
#pragma unroll
    for (int m = 0; m < 8; ++m) {
        float a = bfc1[m];
#pragma unroll
        for (int k = 0; k < 32; ++k) a += h[k] * Wfc1[k * 8 + m];
        z[m] = fmaxf(a, 0.f);
    }
    float o[4];
#pragma unroll
    for (int q = 0; q < 4; ++q) {
        float a = bout[q];
#pragma unroll
        for (int m = 0; m < 8; ++m) a += z[m] * Wout[m * 4 + q];
        o[q] = fmaxf(a, 0.f);
    }
    const float mx = fmaxf(fmaxf(o[0], o[1]), fmaxf(o[2], o[3]));
    const float e0 = expf(o[0] - mx), e1 = expf(o[1] - mx);
    const float e2 = expf(o[2] - mx), e3 = expf(o[3] - mx);
    const float inv = 1.f / (e0 + e1 + e2 + e3);
    out[g * 4 + 0] = e0 * inv;
    out[g * 4 + 1] = e1 * inv;
    out[g * 4 + 2] = e2 * inv;
    out[g * 4 + 3] = e3 * inv;
}

extern "C" void kernel_launch(void* const* d_in, const int* in_sizes, int n_in,
                              void* d_out, int out_size, void* d_ws, size_t ws_size,
                              hipStream_t stream)
{
    const float* x    = (const float*)d_in[0];
    const float* Wn0  = (const float*)d_in[1];
    const float* bn0  = (const float*)d_in[2];
    const float* Ws0  = (const float*)d_in[3];
    const float* Wn   = (const float*)d_in[4];   // [3,32,32]
    const float* bn   = (const float*)d_in[5];   // [3,32]
    const float* Ws   = (const float*)d_in[6];   // [3,32,32]
    const float* Wfc1 = (const float*)d_in[7];
    const float* bfc1 = (const float*)d_in[8];
    const float* Wout = (const float*)d_in[9];
    const float* bout = (const float*)d_in[10];
    const int*   src  = (const int*)d_in[11];
    const int*   dst  = (const int*)d_in[12];
    const int*   gids = (const int*)d_in[13];

    const int n_nodes  = in_sizes[0] / 128;
    const int n_edges  = in_sizes[11];
    const int n_graphs = out_size / 4;
    const size_t N32 = (size_t)n_nodes * 32;

    const int NB = (n_nodes + TILE_NODES - 1) / TILE_NODES;   // 391
    const int C  = (n_edges + CE - 1) / CE;                   // 125
    const int n_off = NB * C;                                  // 48875

    float* A  = (float*)d_ws;            // [N,32]
    float* B0 = A + N32;                 // [N,32]
    float* B1 = B0 + N32;                // [N,32]
    float* hg = B1 + N32;                // [G,32]
    int* histT = (int*)(hg + (size_t)n_graphs * 32);   // [NB*C]
    int* off   = histT + n_off;                        // [NB*C + 1]
    int* part  = off + n_off + 1;                      // [<=256]
    unsigned int* ebuf = (unsigned int*)(part + 256);  // [n_edges]

    const int nparts = (n_off + SCAN_CHUNK - 1) / SCAN_CHUNK;  // 24

    // ---- edge binning (once per call; reused by all 4 layers) ----
    k_hist2<<<C, 1024, 0, stream>>>(dst, histT, n_edges, NB, C);
    k_chunk_sum<<<nparts, 256, 0, stream>>>(histT, part, n_off);
    k_scan_part<<<1, 64, 0, stream>>>(part, nparts);
    k_write_off<<<nparts, 256, 0, stream>>>(histT, part, off, n_off, n_edges);
    k_binfill<<<C, 1024, 0, stream>>>(src, dst, off, ebuf, n_edges, NB, C);

    const int mblocks0 = (n_nodes + 31) / 32;
    const int mblocks  = (n_nodes + 63) / 64;

    // ---- Layer 0 ----
    k_layer0<<<mblocks0, 256, 0, stream>>>(x, Wn0, bn0, Ws0, A, B0, n_nodes);
    k_agg<<<NB, 1024, 0, stream>>>(off, ebuf, A, B0, n_nodes, NB, C, n_edges);

    // ---- Layers 1..3 ----
    float* cur = B0;
    float* nxt = B1;
    for (int l = 0; l < 3; ++l) {
        k_layer<<<mblocks, 256, 0, stream>>>(cur, Wn + l * 1024, bn + l * 32,
                                             Ws + l * 1024, A, nxt, n_nodes);
        k_agg<<<NB, 1024, 0, stream>>>(off, ebuf, A, nxt, n_nodes, NB, C, n_edges);
        float* t = cur; cur = nxt; nxt = t;
    }

    // ---- Pool + head ----
    k_pool<<<n_graphs, 256, 0, stream>>>(cur, gids, hg, n_nodes);
    k_head<<<(n_graphs + 63) / 64, 64, 0, stream>>>(hg, Wfc1, bfc1, Wout, bout,
                                                    (float*)d_out, n_graphs);
}

// Round 4
// 615.751 us; speedup vs baseline: 5.0462x; 5.0462x over previous
//
#include <hip/hip_runtime.h>
#include <hip/hip_bf16.h>
#include <math.h>

// GCN forward: 4 GraphConv layers + sum-pool + FC head + softmax.
// N_NODES=100000, N_EDGES=3200000, N_GRAPHS=64, IN=128, DIM=32.
//
// Round-4 structure:
//  - Two-stage edge sort: (1) segmented bin into 256-dst-node tiles
//    (block-exclusive write regions, no global atomics, low write-amp),
//    (2) per-tile LDS counting sort -> fully dst-sorted eidx + per-node ptr.
//  - Aggregation: atomic-free per-node gather. 8 lanes/node, float4/lane
//    (128B coalesced row per edge), 8-edge unrolled batches for MLP.
//  - Layers run in-place on B (per-node elementwise), saving a buffer.

#define TILE_NODES 256
#define CE 12800                 // edges per sort chunk
#define SCAN_CHUNK 2048
#define MAX_NB 1024

// ---------------- Pass 1: per-chunk histogram over dst tiles ----------------
__global__ __launch_bounds__(1024) void k_hist2(
    const int* __restrict__ dst, int* __restrict__ histT,
    int n_edges, int NB, int C)
{
    __shared__ int hist[MAX_NB];
    const int c = blockIdx.x;
    for (int b = threadIdx.x; b < NB; b += 1024) hist[b] = 0;
    __syncthreads();
    const int beg = c * CE;
    const int end = min(beg + CE, n_edges);
    for (int e = beg + threadIdx.x; e < end; e += 1024)
        atomicAdd(&hist[dst[e] >> 8], 1);
    __syncthreads();
    for (int b = threadIdx.x; b < NB; b += 1024)
        histT[b * C + c] = hist[b];
}

// ---------------- Pass 2: hierarchical exclusive scan of histT ----------------
__global__ __launch_bounds__(256) void k_chunk_sum(
    const int* __restrict__ v, int* __restrict__ part, int n)
{
    __shared__ int red[256];
    const int base = blockIdx.x * SCAN_CHUNK;
    int s = 0;
    for (int i = threadIdx.x; i < SCAN_CHUNK; i += 256) {
        int idx = base + i;
        if (idx < n) s += v[idx];
    }
    red[threadIdx.x] = s;
    __syncthreads();
    for (int off = 128; off > 0; off >>= 1) {
        if (threadIdx.x < off) red[threadIdx.x] += red[threadIdx.x + off];
        __syncthreads();
    }
    if (threadIdx.x == 0) part[blockIdx.x] = red[0];
}

__global__ void k_scan_part(int* __restrict__ part, int nparts)
{
    if (threadIdx.x == 0 && blockIdx.x == 0) {
        int run = 0;
        for (int i = 0; i < nparts; ++i) { int v = part[i]; part[i] = run; run += v; }
    }
}

__global__ __launch_bounds__(256) void k_write_off(
    const int* __restrict__ v, const int* __restrict__ part,
    int* __restrict__ off, int n, int total)
{
    __shared__ int lds[256];
    const int tid   = threadIdx.x;
    const int base  = blockIdx.x * SCAN_CHUNK;
    const int tbase = base + tid * 8;
    int c[8];
    int tot = 0;
#pragma unroll
    for (int m = 0; m < 8; ++m) {
        int idx = tbase + m;
        c[m] = (idx < n) ? v[idx] : 0;
        tot += c[m];
    }
    lds[tid] = tot;
    __syncthreads();
    for (int o = 1; o < 256; o <<= 1) {
        int val = (tid >= o) ? lds[tid - o] : 0;
        __syncthreads();
        lds[tid] += val;
        __syncthreads();
    }
    int run = part[blockIdx.x] + lds[tid] - tot;
#pragma unroll
    for (int m = 0; m < 8; ++m) {
        int idx = tbase + m;
        if (idx < n) off[idx] = run;
        run += c[m];
    }
    if (blockIdx.x == 0 && tid == 0) off[n] = total;
}

// ---------------- Pass 3: bin packed edges into tile regions ----------------
__global__ __launch_bounds__(1024) void k_binfill(
    const int* __restrict__ src, const int* __restrict__ dst,
    const int* __restrict__ off, unsigned int* __restrict__ ebuf,
    int n_edges, int NB, int C)
{
    __shared__ int lcur[MAX_NB];
    const int c = blockIdx.x;
    for (int b = threadIdx.x; b < NB; b += 1024)
        lcur[b] = off[b * C + c];
    __syncthreads();
    const int beg = c * CE;
    const int end = min(beg + CE, n_edges);
    for (int e = beg + threadIdx.x; e < end; e += 1024) {
        const int d = dst[e];
        const int b = d >> 8;
        const unsigned int dl = (unsigned int)(d & 255);
        const int pos = atomicAdd(&lcur[b], 1);
        ebuf[pos] = (dl << 17) | (unsigned int)src[e];
    }
}

// ---------------- Pass 4: per-tile counting sort -> eidx + ptr ----------------
__global__ __launch_bounds__(1024) void k_tile_sort(
    const int* __restrict__ off, const unsigned int* __restrict__ ebuf,
    int* __restrict__ eidx, int* __restrict__ ptr,
    int n_nodes, int NB, int C, int n_edges)
{
    __shared__ int hist[TILE_NODES];
    __shared__ int scan[TILE_NODES];
    __shared__ int cur[TILE_NODES];
    const int t = blockIdx.x;
    const int beg = off[t * C];
    const int end = (t + 1 < NB) ? off[(t + 1) * C] : n_edges;
    const int node_base = t * TILE_NODES;
    const int n_valid = min(TILE_NODES, n_nodes - node_base);

    if (threadIdx.x < TILE_NODES) hist[threadIdx.x] = 0;
    __syncthreads();
    for (int e = beg + threadIdx.x; e < end; e += 1024)
        atomicAdd(&hist[ebuf[e] >> 17], 1);
    __syncthreads();
    if (threadIdx.x < TILE_NODES) scan[threadIdx.x] = hist[threadIdx.x];
    __syncthreads();
    for (int o = 1; o < TILE_NODES; o <<= 1) {
        int v = 0;
        if (threadIdx.x < TILE_NODES && threadIdx.x >= o) v = scan[threadIdx.x - o];
        __syncthreads();
        if (threadIdx.x < TILE_NODES) scan[threadIdx.x] += v;
        __syncthreads();
    }
    if (threadIdx.x < TILE_NODES) {
        const int ex = scan[threadIdx.x] - hist[threadIdx.x];   // exclusive
        cur[threadIdx.x] = ex;
        if (threadIdx.x < n_valid) ptr[node_base + threadIdx.x] = beg + ex;
    }
    if (t == NB - 1 && threadIdx.x == 0) ptr[n_nodes] = n_edges;
    __syncthreads();
    for (int e = beg + threadIdx.x; e < end; e += 1024) {
        const unsigned int v = ebuf[e];
        const int dl = (int)(v >> 17);
        const int pos = beg + atomicAdd(&cur[dl], 1);
        eidx[pos] = (int)(v & 0x1FFFFu);
    }
}

// ---------------- Layer 0: A = x@Wn0 ; B = x@Ws0 + bn0 ----------------
__global__ __launch_bounds__(256) void k_layer0(
    const float* __restrict__ x, const float* __restrict__ Wn0,
    const float* __restrict__ bn0, const float* __restrict__ Ws0,
    float* __restrict__ A, float* __restrict__ B, int n_nodes)
{
    __shared__ float sWn[128 * 32];
    __shared__ float sWs[128 * 32];
    __shared__ float sx[32 * 128];

    for (int i = threadIdx.x; i < 128 * 32; i += 256) {
        sWn[i] = Wn0[i];
        sWs[i] = Ws0[i];
    }
    const int tile = blockIdx.x * 32;
    {
        const float4* s4 = (const float4*)(x + (size_t)tile * 128);
        const int lim = (n_nodes - tile) * 32;
#pragma unroll
        for (int m = 0; m < 4; ++m) {
            int i = threadIdx.x + m * 256;
            if (i < lim) ((float4*)sx)[i] = s4[i];
        }
    }
    const int j = threadIdx.x & 31;
    const int r = threadIdx.x >> 5;
    const float bias = bn0[j];
    __syncthreads();

    float accA[4] = {0.f, 0.f, 0.f, 0.f};
    float accB[4] = {bias, bias, bias, bias};
#pragma unroll 8
    for (int k = 0; k < 128; ++k) {
        const float wn = sWn[k * 32 + j];
        const float ws = sWs[k * 32 + j];
#pragma unroll
        for (int m = 0; m < 4; ++m) {
            const float xv = sx[(r + 8 * m) * 128 + k];
            accA[m] += xv * wn;
            accB[m] += xv * ws;
        }
    }
#pragma unroll
    for (int m = 0; m < 4; ++m) {
        const int node = tile + r + 8 * m;
        if (node < n_nodes) {
            A[(size_t)node * 32 + j] = accA[m];
            B[(size_t)node * 32 + j] = accB[m];
        }
    }
}

// ------------- Layers 1..3 (in-place on B): A = relu(B)@Wn ; B = relu(B)@Ws + bn -------------
__global__ __launch_bounds__(256) void k_layer(
    float* HB,                       // read pre-act, overwritten with new B
    const float* __restrict__ Wn, const float* __restrict__ bnv,
    const float* __restrict__ Ws, float* __restrict__ A, int n_nodes)
{
    __shared__ float sWn[32 * 32];
    __shared__ float sWs[32 * 32];
    __shared__ float sh[64 * 32];

    for (int i = threadIdx.x; i < 1024; i += 256) {
        sWn[i] = Wn[i];
        sWs[i] = Ws[i];
    }
    const int tile = blockIdx.x * 64;
    {
        const float4* s4 = (const float4*)(HB + (size_t)tile * 32);
        const int lim = (n_nodes - tile) * 8;
#pragma unroll
        for (int m = 0; m < 2; ++m) {
            int i = threadIdx.x + m * 256;
            if (i < lim) {
                float4 v = s4[i];
                v.x = fmaxf(v.x, 0.f); v.y = fmaxf(v.y, 0.f);
                v.z = fmaxf(v.z, 0.f); v.w = fmaxf(v.w, 0.f);
                ((float4*)sh)[i] = v;
            }
        }
    }
    const int j = threadIdx.x & 31;
    const int r = threadIdx.x >> 5;
    const float bias = bnv[j];
    __syncthreads();

    float accA[8] = {0.f};
    float accB[8];
#pragma unroll
    for (int m = 0; m < 8; ++m) accB[m] = bias;
#pragma unroll
    for (int k = 0; k < 32; ++k) {
        const float wn = sWn[k * 32 + j];
        const float ws = sWs[k * 32 + j];
#pragma unroll
        for (int m = 0; m < 8; ++m) {
            const float hv = sh[(r + 8 * m) * 32 + k];
            accA[m] += hv * wn;
            accB[m] += hv * ws;
        }
    }
#pragma unroll
    for (int m = 0; m < 8; ++m) {
        const int node = tile + r + 8 * m;
        if (node < n_nodes) {
            A[(size_t)node * 32 + j] = accA[m];
            HB[(size_t)node * 32 + j] = accB[m];
        }
    }
}

// ------------- Aggregation: B[n] += sum_{e in CSR[n]} A[eidx[e]] -------------
// 8 lanes per node (float4 each = 128B row), 8-edge unrolled batches.
__global__ __launch_bounds__(256) void k_agg2(
    const int* __restrict__ ptr, const int* __restrict__ eidx,
    const float* __restrict__ A, float* __restrict__ B, int n_nodes)
{
    const int g    = blockIdx.x * 32 + (threadIdx.x >> 3);
    const int lane = threadIdx.x & 7;
    if (g >= n_nodes) return;
    const int beg = ptr[g];
    const int end = ptr[g + 1];
    const float4* __restrict__ A4 = (const float4*)A;
    float4* B4 = (float4*)B;

    float4 acc = B4[(size_t)g * 8 + lane];   // self + bias from layer kernel
    for (int e = beg; e < end; e += 8) {
        int idx[8];
#pragma unroll
        for (int u = 0; u < 8; ++u)
            idx[u] = (e + u < end) ? eidx[e + u] : -1;
#pragma unroll
        for (int u = 0; u < 8; ++u) {
            if (idx[u] >= 0) {
                const float4 a = A4[(size_t)idx[u] * 8 + lane];
                acc.x += a.x; acc.y += a.y; acc.z += a.z; acc.w += a.w;
            }
        }
    }
    B4[(size_t)g * 8 + lane] = acc;
}

// ---------------- Per-graph sum pool ----------------
__global__ __launch_bounds__(256) void k_pool(
    const float* __restrict__ H, const int* __restrict__ gids,
    float* __restrict__ hg, int n_nodes)
{
    const int g = blockIdx.x;
    int lo = 0, hi = n_nodes;
    while (lo < hi) { int m = (lo + hi) >> 1; if (gids[m] < g) lo = m + 1; else hi = m; }
    const int start = lo;
    hi = n_nodes;
    while (lo < hi) { int m = (lo + hi) >> 1; if (gids[m] < g + 1) lo = m + 1; else hi = m; }
    const int end = lo;

    const int j = threadIdx.x & 31;
    const int s = threadIdx.x >> 5;
    float acc = 0.f;
    for (int n = start + s; n < end; n += 8)
        acc += fmaxf(H[(size_t)n * 32 + j], 0.f);

    __shared__ float red[256];
    red[threadIdx.x] = acc;
    __syncthreads();
    if (s == 0) {
        float t = 0.f;
#pragma unroll
        for (int k = 0; k < 8; ++k) t += red[k * 32 + j];
        hg[g * 32 + j] = t;
    }
}

// ---------------- FC head + softmax ----------------
__global__ __launch_bounds__(64) void k_head(
    const float* __restrict__ hg,
    const float* __restrict__ Wfc1, const float* __restrict__ bfc1,
    const float* __restrict__ Wout, const float* __restrict__ bout,
    float* __restrict__ out, int n_graphs)
{
    const int g = blockIdx.x * blockDim.x + threadIdx.x;
    if (g >= n_graphs) return;
    float h[32];
#pragma unroll
    for (int k = 0; k < 32; ++k) h[k] = hg[g * 32 + k];
    float z[8];
#pragma unroll
    for (int m = 0; m < 8; ++m) {
        float a = bfc1[m];
#pragma unroll
        for (int k = 0; k < 32; ++k) a += h[k] * Wfc1[k * 8 + m];
        z[m] = fmaxf(a, 0.f);
    }
    float o[4];
#pragma unroll
    for (int q = 0; q < 4; ++q) {
        float a = bout[q];
#pragma unroll
        for (int m = 0; m < 8; ++m) a += z[m] * Wout[m * 4 + q];
        o[q] = fmaxf(a, 0.f);
    }
    const float mx = fmaxf(fmaxf(o[0], o[1]), fmaxf(o[2], o[3]));
    const float e0 = expf(o[0] - mx), e1 = expf(o[1] - mx);
    const float e2 = expf(o[2] - mx), e3 = expf(o[3] - mx);
    const float inv = 1.f / (e0 + e1 + e2 + e3);
    out[g * 4 + 0] = e0 * inv;
    out[g * 4 + 1] = e1 * inv;
    out[g * 4 + 2] = e2 * inv;
    out[g * 4 + 3] = e3 * inv;
}

extern "C" void kernel_launch(void* const* d_in, const int* in_sizes, int n_in,
                              void* d_out, int out_size, void* d_ws, size_t ws_size,
                              hipStream_t stream)
{
    const float* x    = (const float*)d_in[0];
    const float* Wn0  = (const float*)d_in[1];
    const float* bn0  = (const float*)d_in[2];
    const float* Ws0  = (const float*)d_in[3];
    const float* Wn   = (const float*)d_in[4];   // [3,32,32]
    const float* bn   = (const float*)d_in[5];   // [3,32]
    const float* Ws   = (const float*)d_in[6];   // [3,32,32]
    const float* Wfc1 = (const float*)d_in[7];
    const float* bfc1 = (const float*)d_in[8];
    const float* Wout = (const float*)d_in[9];
    const float* bout = (const float*)d_in[10];
    const int*   src  = (const int*)d_in[11];
    const int*   dst  = (const int*)d_in[12];
    const int*   gids = (const int*)d_in[13];

    const int n_nodes  = in_sizes[0] / 128;
    const int n_edges  = in_sizes[11];
    const int n_graphs = out_size / 4;
    const size_t N32 = (size_t)n_nodes * 32;

    const int NB = (n_nodes + TILE_NODES - 1) / TILE_NODES;   // 391
    const int C  = (n_edges + CE - 1) / CE;                   // 250
    const int n_off = NB * C;

    float* A  = (float*)d_ws;                           // [N,32]
    float* B  = A + N32;                                // [N,32] (in-place)
    float* hg = B + N32;                                // [G,32]
    int* histT = (int*)(hg + (size_t)n_graphs * 32);    // [NB*C]
    int* off   = histT + n_off;                         // [NB*C + 1]
    int* part  = off + n_off + 1;                       // [<=256]
    int* ptr   = part + 256;                            // [N+1]
    unsigned int* ebuf = (unsigned int*)(ptr + n_nodes + 1);  // [E]
    int* eidx  = (int*)(ebuf + n_edges);                // [E]

    const int nparts = (n_off + SCAN_CHUNK - 1) / SCAN_CHUNK;

    // ---- edge sort (once per call; reused by all 4 layers) ----
    k_hist2<<<C, 1024, 0, stream>>>(dst, histT, n_edges, NB, C);
    k_chunk_sum<<<nparts, 256, 0, stream>>>(histT, part, n_off);
    k_scan_part<<<1, 64, 0, stream>>>(part, nparts);
    k_write_off<<<nparts, 256, 0, stream>>>(histT, part, off, n_off, n_edges);
    k_binfill<<<C, 1024, 0, stream>>>(src, dst, off, ebuf, n_edges, NB, C);
    k_tile_sort<<<NB, 1024, 0, stream>>>(off, ebuf, eidx, ptr, n_nodes, NB, C, n_edges);

    const int mblocks0 = (n_nodes + 31) / 32;
    const int mblocks  = (n_nodes + 63) / 64;
    const int ablocks  = (n_nodes + 31) / 32;

    // ---- Layer 0 ----
    k_layer0<<<mblocks0, 256, 0, stream>>>(x, Wn0, bn0, Ws0, A, B, n_nodes);
    k_agg2<<<ablocks, 256, 0, stream>>>(ptr, eidx, A, B, n_nodes);

    // ---- Layers 1..3 (in-place on B) ----
    for (int l = 0; l < 3; ++l) {
        k_layer<<<mblocks, 256, 0, stream>>>(B, Wn + l * 1024, bn + l * 32,
                                             Ws + l * 1024, A, n_nodes);
        k_agg2<<<ablocks, 256, 0, stream>>>(ptr, eidx, A, B, n_nodes);
    }

    // ---- Pool + head ----
    k_pool<<<n_graphs, 256, 0, stream>>>(B, gids, hg, n_nodes);
    k_head<<<(n_graphs + 63) / 64, 64, 0, stream>>>(hg, Wfc1, bfc1, Wout, bout,
                                                    (float*)d_out, n_graphs);
}

// Round 5
// 578.520 us; speedup vs baseline: 5.3709x; 1.0644x over previous
//
#include <hip/hip_runtime.h>
#include <hip/hip_bf16.h>
#include <math.h>

// GCN forward: 4 GraphConv layers + sum-pool + FC head + softmax.
// N_NODES=100000, N_EDGES=3200000, N_GRAPHS=64, IN=128, DIM=32.
//
// Round-5: round-4 structure + node-parallel pooling (k_pool was 66 us at
// 2.3% occupancy with one block per graph; now 782 blocks + boundary-flush
// atomics into hg).

#define TILE_NODES 256
#define CE 12800                 // edges per sort chunk
#define SCAN_CHUNK 2048
#define MAX_NB 1024

// ---------------- Pass 1: per-chunk histogram over dst tiles ----------------
__global__ __launch_bounds__(1024) void k_hist2(
    const int* __restrict__ dst, int* __restrict__ histT,
    int n_edges, int NB, int C)
{
    __shared__ int hist[MAX_NB];
    const int c = blockIdx.x;
    for (int b = threadIdx.x; b < NB; b += 1024) hist[b] = 0;
    __syncthreads();
    const int beg = c * CE;
    const int end = min(beg + CE, n_edges);
    for (int e = beg + threadIdx.x; e < end; e += 1024)
        atomicAdd(&hist[dst[e] >> 8], 1);
    __syncthreads();
    for (int b = threadIdx.x; b < NB; b += 1024)
        histT[b * C + c] = hist[b];
}

// ---------------- Pass 2: hierarchical exclusive scan of histT ----------------
__global__ __launch_bounds__(256) void k_chunk_sum(
    const int* __restrict__ v, int* __restrict__ part, int n)
{
    __shared__ int red[256];
    const int base = blockIdx.x * SCAN_CHUNK;
    int s = 0;
    for (int i = threadIdx.x; i < SCAN_CHUNK; i += 256) {
        int idx = base + i;
        if (idx < n) s += v[idx];
    }
    red[threadIdx.x] = s;
    __syncthreads();
    for (int off = 128; off > 0; off >>= 1) {
        if (threadIdx.x < off) red[threadIdx.x] += red[threadIdx.x + off];
        __syncthreads();
    }
    if (threadIdx.x == 0) part[blockIdx.x] = red[0];
}

__global__ void k_scan_part(int* __restrict__ part, int nparts)
{
    if (threadIdx.x == 0 && blockIdx.x == 0) {
        int run = 0;
        for (int i = 0; i < nparts; ++i) { int v = part[i]; part[i] = run; run += v; }
    }
}

__global__ __launch_bounds__(256) void k_write_off(
    const int* __restrict__ v, const int* __restrict__ part,
    int* __restrict__ off, int n, int total)
{
    __shared__ int lds[256];
    const int tid   = threadIdx.x;
    const int base  = blockIdx.x * SCAN_CHUNK;
    const int tbase = base + tid * 8;
    int c[8];
    int tot = 0;
#pragma unroll
    for (int m = 0; m < 8; ++m) {
        int idx = tbase + m;
        c[m] = (idx < n) ? v[idx] : 0;
        tot += c[m];
    }
    lds[tid] = tot;
    __syncthreads();
    for (int o = 1; o < 256; o <<= 1) {
        int val = (tid >= o) ? lds[tid - o] : 0;
        __syncthreads();
        lds[tid] += val;
        __syncthreads();
    }
    int run = part[blockIdx.x] + lds[tid] - tot;
#pragma unroll
    for (int m = 0; m < 8; ++m) {
        int idx = tbase + m;
        if (idx < n) off[idx] = run;
        run += c[m];
    }
    if (blockIdx.x == 0 && tid == 0) off[n] = total;
}

// ---------------- Pass 3: bin packed edges into tile regions ----------------
__global__ __launch_bounds__(1024) void k_binfill(
    const int* __restrict__ src, const int* __restrict__ dst,
    const int* __restrict__ off, unsigned int* __restrict__ ebuf,
    int n_edges, int NB, int C)
{
    __shared__ int lcur[MAX_NB];
    const int c = blockIdx.x;
    for (int b = threadIdx.x; b < NB; b += 1024)
        lcur[b] = off[b * C + c];
    __syncthreads();
    const int beg = c * CE;
    const int end = min(beg + CE, n_edges);
    for (int e = beg + threadIdx.x; e < end; e += 1024) {
        const int d = dst[e];
        const int b = d >> 8;
        const unsigned int dl = (unsigned int)(d & 255);
        const int pos = atomicAdd(&lcur[b], 1);
        ebuf[pos] = (dl << 17) | (unsigned int)src[e];
    }
}

// ---------------- Pass 4: per-tile counting sort -> eidx + ptr ----------------
__global__ __launch_bounds__(1024) void k_tile_sort(
    const int* __restrict__ off, const unsigned int* __restrict__ ebuf,
    int* __restrict__ eidx, int* __restrict__ ptr,
    int n_nodes, int NB, int C, int n_edges)
{
    __shared__ int hist[TILE_NODES];
    __shared__ int scan[TILE_NODES];
    __shared__ int cur[TILE_NODES];
    const int t = blockIdx.x;
    const int beg = off[t * C];
    const int end = (t + 1 < NB) ? off[(t + 1) * C] : n_edges;
    const int node_base = t * TILE_NODES;
    const int n_valid = min(TILE_NODES, n_nodes - node_base);

    if (threadIdx.x < TILE_NODES) hist[threadIdx.x] = 0;
    __syncthreads();
    for (int e = beg + threadIdx.x; e < end; e += 1024)
        atomicAdd(&hist[ebuf[e] >> 17], 1);
    __syncthreads();
    if (threadIdx.x < TILE_NODES) scan[threadIdx.x] = hist[threadIdx.x];
    __syncthreads();
    for (int o = 1; o < TILE_NODES; o <<= 1) {
        int v = 0;
        if (threadIdx.x < TILE_NODES && threadIdx.x >= o) v = scan[threadIdx.x - o];
        __syncthreads();
        if (threadIdx.x < TILE_NODES) scan[threadIdx.x] += v;
        __syncthreads();
    }
    if (threadIdx.x < TILE_NODES) {
        const int ex = scan[threadIdx.x] - hist[threadIdx.x];   // exclusive
        cur[threadIdx.x] = ex;
        if (threadIdx.x < n_valid) ptr[node_base + threadIdx.x] = beg + ex;
    }
    if (t == NB - 1 && threadIdx.x == 0) ptr[n_nodes] = n_edges;
    __syncthreads();
    for (int e = beg + threadIdx.x; e < end; e += 1024) {
        const unsigned int v = ebuf[e];
        const int dl = (int)(v >> 17);
        const int pos = beg + atomicAdd(&cur[dl], 1);
        eidx[pos] = (int)(v & 0x1FFFFu);
    }
}

// ---------------- Layer 0: A = x@Wn0 ; B = x@Ws0 + bn0 ----------------
__global__ __launch_bounds__(256) void k_layer0(
    const float* __restrict__ x, const float* __restrict__ Wn0,
    const float* __restrict__ bn0, const float* __restrict__ Ws0,
    float* __restrict__ A, float* __restrict__ B, int n_nodes)
{
    __shared__ float sWn[128 * 32];
    __shared__ float sWs[128 * 32];
    __shared__ float sx[32 * 128];

    for (int i = threadIdx.x; i < 128 * 32; i += 256) {
        sWn[i] = Wn0[i];
        sWs[i] = Ws0[i];
    }
    const int tile = blockIdx.x * 32;
    {
        const float4* s4 = (const float4*)(x + (size_t)tile * 128);
        const int lim = (n_nodes - tile) * 32;
#pragma unroll
        for (int m = 0; m < 4; ++m) {
            int i = threadIdx.x + m * 256;
            if (i < lim) ((float4*)sx)[i] = s4[i];
        }
    }
    const int j = threadIdx.x & 31;
    const int r = threadIdx.x >> 5;
    const float bias = bn0[j];
    __syncthreads();

    float accA[4] = {0.f, 0.f, 0.f, 0.f};
    float accB[4] = {bias, bias, bias, bias};
#pragma unroll 8
    for (int k = 0; k < 128; ++k) {
        const float wn = sWn[k * 32 + j];
        const float ws = sWs[k * 32 + j];
#pragma unroll
        for (int m = 0; m < 4; ++m) {
            const float xv = sx[(r + 8 * m) * 128 + k];
            accA[m] += xv * wn;
            accB[m] += xv * ws;
        }
    }
#pragma unroll
    for (int m = 0; m < 4; ++m) {
        const int node = tile + r + 8 * m;
        if (node < n_nodes) {
            A[(size_t)node * 32 + j] = accA[m];
            B[(size_t)node * 32 + j] = accB[m];
        }
    }
}

// ------------- Layers 1..3 (in-place on B): A = relu(B)@Wn ; B = relu(B)@Ws + bn -------------
__global__ __launch_bounds__(256) void k_layer(
    float* HB,                       // read pre-act, overwritten with new B
    const float* __restrict__ Wn, const float* __restrict__ bnv,
    const float* __restrict__ Ws, float* __restrict__ A, int n_nodes)
{
    __shared__ float sWn[32 * 32];
    __shared__ float sWs[32 * 32];
    __shared__ float sh[64 * 32];

    for (int i = threadIdx.x; i < 1024; i += 256) {
        sWn[i] = Wn[i];
        sWs[i] = Ws[i];
    }
    const int tile = blockIdx.x * 64;
    {
        const float4* s4 = (const float4*)(HB + (size_t)tile * 32);
        const int lim = (n_nodes - tile) * 8;
#pragma unroll
        for (int m = 0; m < 2; ++m) {
            int i = threadIdx.x + m * 256;
            if (i < lim) {
                float4 v = s4[i];
                v.x = fmaxf(v.x, 0.f); v.y = fmaxf(v.y, 0.f);
                v.z = fmaxf(v.z, 0.f); v.w = fmaxf(v.w, 0.f);
                ((float4*)sh)[i] = v;
            }
        }
    }
    const int j = threadIdx.x & 31;
    const int r = threadIdx.x >> 5;
    const float bias = bnv[j];
    __syncthreads();

    float accA[8] = {0.f};
    float accB[8];
#pragma unroll
    for (int m = 0; m < 8; ++m) accB[m] = bias;
#pragma unroll
    for (int k = 0; k < 32; ++k) {
        const float wn = sWn[k * 32 + j];
        const float ws = sWs[k * 32 + j];
#pragma unroll
        for (int m = 0; m < 8; ++m) {
            const float hv = sh[(r + 8 * m) * 32 + k];
            accA[m] += hv * wn;
            accB[m] += hv * ws;
        }
    }
#pragma unroll
    for (int m = 0; m < 8; ++m) {
        const int node = tile + r + 8 * m;
        if (node < n_nodes) {
            A[(size_t)node * 32 + j] = accA[m];
            HB[(size_t)node * 32 + j] = accB[m];
        }
    }
}

// ------------- Aggregation: B[n] += sum_{e in CSR[n]} A[eidx[e]] -------------
// 8 lanes per node (float4 each = 128B row), 8-edge unrolled batches.
__global__ __launch_bounds__(256) void k_agg2(
    const int* __restrict__ ptr, const int* __restrict__ eidx,
    const float* __restrict__ A, float* __restrict__ B, int n_nodes)
{
    const int g    = blockIdx.x * 32 + (threadIdx.x >> 3);
    const int lane = threadIdx.x & 7;
    if (g >= n_nodes) return;
    const int beg = ptr[g];
    const int end = ptr[g + 1];
    const float4* __restrict__ A4 = (const float4*)A;
    float4* B4 = (float4*)B;

    float4 acc = B4[(size_t)g * 8 + lane];   // self + bias from layer kernel
    for (int e = beg; e < end; e += 8) {
        int idx[8];
#pragma unroll
        for (int u = 0; u < 8; ++u)
            idx[u] = (e + u < end) ? eidx[e + u] : -1;
#pragma unroll
        for (int u = 0; u < 8; ++u) {
            if (idx[u] >= 0) {
                const float4 a = A4[(size_t)idx[u] * 8 + lane];
                acc.x += a.x; acc.y += a.y; acc.z += a.z; acc.w += a.w;
            }
        }
    }
    B4[(size_t)g * 8 + lane] = acc;
}

// ---------------- Zero hg ----------------
__global__ __launch_bounds__(256) void k_zero_f(float* __restrict__ p, int n)
{
    int i = blockIdx.x * 256 + threadIdx.x;
    if (i < n) p[i] = 0.f;
}

// ---------------- Node-parallel per-graph sum pool ----------------
// 128 nodes per block; thread (j=tid&31, r=tid>>5) walks rows r, r+8, ...
// graph_ids sorted -> accumulate run in registers, atomicAdd on boundary.
__global__ __launch_bounds__(256) void k_pool1(
    const float* __restrict__ H, const int* __restrict__ gids,
    float* __restrict__ hg, int n_nodes)
{
    const int base = blockIdx.x * 128;
    const int lim  = min(base + 128, n_nodes);
    const int j = threadIdx.x & 31;
    const int r = threadIdx.x >> 5;

    int curg = -1;
    float acc = 0.f;
    for (int n = base + r; n < lim; n += 8) {
        const int g = gids[n];
        const float v = fmaxf(H[(size_t)n * 32 + j], 0.f);
        if (g != curg) {
            if (curg >= 0) atomicAdd(&hg[curg * 32 + j], acc);
            curg = g;
            acc = v;
        } else {
            acc += v;
        }
    }
    if (curg >= 0) atomicAdd(&hg[curg * 32 + j], acc);
}

// ---------------- FC head + softmax ----------------
__global__ __launch_bounds__(64) void k_head(
    const float* __restrict__ hg,
    const float* __restrict__ Wfc1, const float* __restrict__ bfc1,
    const float* __restrict__ Wout, const float* __restrict__ bout,
    float* __restrict__ out, int n_graphs)
{
    const int g = blockIdx.x * blockDim.x + threadIdx.x;
    if (g >= n_graphs) return;
    float h[32];
#pragma unroll
    for (int k = 0; k < 32; ++k) h[k] = hg[g * 32 + k];
    float z[8];
#pragma unroll
    for (int m = 0; m < 8; ++m) {
        float a = bfc1[m];
#pragma unroll
        for (int k = 0; k < 32; ++k) a += h[k] * Wfc1[k * 8 + m];
        z[m] = fmaxf(a, 0.f);
    }
    float o[4];
#pragma unroll
    for (int q = 0; q < 4; ++q) {
        float a = bout[q];
#pragma unroll
        for (int m = 0; m < 8; ++m) a += z[m] * Wout[m * 4 + q];
        o[q] = fmaxf(a, 0.f);
    }
    const float mx = fmaxf(fmaxf(o[0], o[1]), fmaxf(o[2], o[3]));
    const float e0 = expf(o[0] - mx), e1 = expf(o[1] - mx);
    const float e2 = expf(o[2] - mx), e3 = expf(o[3] - mx);
    const float inv = 1.f / (e0 + e1 + e2 + e3);
    out[g * 4 + 0] = e0 * inv;
    out[g * 4 + 1] = e1 * inv;
    out[g * 4 + 2] = e2 * inv;
    out[g * 4 + 3] = e3 * inv;
}

extern "C" void kernel_launch(void* const* d_in, const int* in_sizes, int n_in,
                              void* d_out, int out_size, void* d_ws, size_t ws_size,
                              hipStream_t stream)
{
    const float* x    = (const float*)d_in[0];
    const float* Wn0  = (const float*)d_in[1];
    const float* bn0  = (const float*)d_in[2];
    const float* Ws0  = (const float*)d_in[3];
    const float* Wn   = (const float*)d_in[4];   // [3,32,32]
    const float* bn   = (const float*)d_in[5];   // [3,32]
    const float* Ws   = (const float*)d_in[6];   // [3,32,32]
    const float* Wfc1 = (const float*)d_in[7];
    const float* bfc1 = (const float*)d_in[8];
    const float* Wout = (const float*)d_in[9];
    const float* bout = (const float*)d_in[10];
    const int*   src  = (const int*)d_in[11];
    const int*   dst  = (const int*)d_in[12];
    const int*   gids = (const int*)d_in[13];

    const int n_nodes  = in_sizes[0] / 128;
    const int n_edges  = in_sizes[11];
    const int n_graphs = out_size / 4;
    const size_t N32 = (size_t)n_nodes * 32;

    const int NB = (n_nodes + TILE_NODES - 1) / TILE_NODES;   // 391
    const int C  = (n_edges + CE - 1) / CE;                   // 250
    const int n_off = NB * C;

    float* A  = (float*)d_ws;                           // [N,32]
    float* B  = A + N32;                                // [N,32] (in-place)
    float* hg = B + N32;                                // [G,32]
    int* histT = (int*)(hg + (size_t)n_graphs * 32);    // [NB*C]
    int* off   = histT + n_off;                         // [NB*C + 1]
    int* part  = off + n_off + 1;                       // [<=256]
    int* ptr   = part + 256;                            // [N+1]
    unsigned int* ebuf = (unsigned int*)(ptr + n_nodes + 1);  // [E]
    int* eidx  = (int*)(ebuf + n_edges);                // [E]

    const int nparts = (n_off + SCAN_CHUNK - 1) / SCAN_CHUNK;

    // ---- edge sort (once per call; reused by all 4 layers) ----
    k_hist2<<<C, 1024, 0, stream>>>(dst, histT, n_edges, NB, C);
    k_chunk_sum<<<nparts, 256, 0, stream>>>(histT, part, n_off);
    k_scan_part<<<1, 64, 0, stream>>>(part, nparts);
    k_write_off<<<nparts, 256, 0, stream>>>(histT, part, off, n_off, n_edges);
    k_binfill<<<C, 1024, 0, stream>>>(src, dst, off, ebuf, n_edges, NB, C);
    k_tile_sort<<<NB, 1024, 0, stream>>>(off, ebuf, eidx, ptr, n_nodes, NB, C, n_edges);

    const int mblocks0 = (n_nodes + 31) / 32;
    const int mblocks  = (n_nodes + 63) / 64;
    const int ablocks  = (n_nodes + 31) / 32;

    // ---- Layer 0 ----
    k_layer0<<<mblocks0, 256, 0, stream>>>(x, Wn0, bn0, Ws0, A, B, n_nodes);
    k_agg2<<<ablocks, 256, 0, stream>>>(ptr, eidx, A, B, n_nodes);

    // ---- Layers 1..3 (in-place on B) ----
    for (int l = 0; l < 3; ++l) {
        k_layer<<<mblocks, 256, 0, stream>>>(B, Wn + l * 1024, bn + l * 32,
                                             Ws + l * 1024, A, n_nodes);
        k_agg2<<<ablocks, 256, 0, stream>>>(ptr, eidx, A, B, n_nodes);
    }

    // ---- Pool + head ----
    k_zero_f<<<(n_graphs * 32 + 255) / 256, 256, 0, stream>>>(hg, n_graphs * 32);
    k_pool1<<<(n_nodes + 127) / 128, 256, 0, stream>>>(B, gids, hg, n_nodes);
    k_head<<<(n_graphs + 63) / 64, 64, 0, stream>>>(hg, Wfc1, bfc1, Wout, bout,
                                                    (float*)d_out, n_graphs);
}

// Round 6
// 525.798 us; speedup vs baseline: 5.9095x; 1.1003x over previous
//
#include <hip/hip_runtime.h>
#include <hip/hip_bf16.h>
#include <math.h>

// GCN forward: 4 GraphConv layers + sum-pool + FC head + softmax.
// N_NODES=100000, N_EDGES=3200000, N_GRAPHS=64, IN=128, DIM=32.
//
// Round-6: round-5 structure + A (neighbor-transform matrix) stored as bf16.
// The edge gather was fetch-bound (177 MB/dispatch from a 12.8 MB fp32 table
// that doesn't fit per-XCD L2); bf16 halves logical gather traffic and nearly
// fits the 4 MB L2. Accumulation stays fp32; self-path + bias stay fp32.

#define TILE_NODES 256
#define CE 12800                 // edges per sort chunk
#define SCAN_CHUNK 2048
#define MAX_NB 1024

__device__ inline ushort f2bf(float f) {
    unsigned u = __float_as_uint(f);
    unsigned r = (u + 0x7FFFu + ((u >> 16) & 1u)) >> 16;   // RTN-even
    return (ushort)r;
}
__device__ inline float bf_lo(unsigned u) { return __uint_as_float(u << 16); }
__device__ inline float bf_hi(unsigned u) { return __uint_as_float(u & 0xFFFF0000u); }

// ---------------- Pass 1: per-chunk histogram over dst tiles ----------------
__global__ __launch_bounds__(1024) void k_hist2(
    const int* __restrict__ dst, int* __restrict__ histT,
    int n_edges, int NB, int C)
{
    __shared__ int hist[MAX_NB];
    const int c = blockIdx.x;
    for (int b = threadIdx.x; b < NB; b += 1024) hist[b] = 0;
    __syncthreads();
    const int beg = c * CE;
    const int end = min(beg + CE, n_edges);
    for (int e = beg + threadIdx.x; e < end; e += 1024)
        atomicAdd(&hist[dst[e] >> 8], 1);
    __syncthreads();
    for (int b = threadIdx.x; b < NB; b += 1024)
        histT[b * C + c] = hist[b];
}

// ---------------- Pass 2: hierarchical exclusive scan of histT ----------------
__global__ __launch_bounds__(256) void k_chunk_sum(
    const int* __restrict__ v, int* __restrict__ part, int n)
{
    __shared__ int red[256];
    const int base = blockIdx.x * SCAN_CHUNK;
    int s = 0;
    for (int i = threadIdx.x; i < SCAN_CHUNK; i += 256) {
        int idx = base + i;
        if (idx < n) s += v[idx];
    }
    red[threadIdx.x] = s;
    __syncthreads();
    for (int off = 128; off > 0; off >>= 1) {
        if (threadIdx.x < off) red[threadIdx.x] += red[threadIdx.x + off];
        __syncthreads();
    }
    if (threadIdx.x == 0) part[blockIdx.x] = red[0];
}

__global__ void k_scan_part(int* __restrict__ part, int nparts)
{
    if (threadIdx.x == 0 && blockIdx.x == 0) {
        int run = 0;
        for (int i = 0; i < nparts; ++i) { int v = part[i]; part[i] = run; run += v; }
    }
}

__global__ __launch_bounds__(256) void k_write_off(
    const int* __restrict__ v, const int* __restrict__ part,
    int* __restrict__ off, int n, int total)
{
    __shared__ int lds[256];
    const int tid   = threadIdx.x;
    const int base  = blockIdx.x * SCAN_CHUNK;
    const int tbase = base + tid * 8;
    int c[8];
    int tot = 0;
#pragma unroll
    for (int m = 0; m < 8; ++m) {
        int idx = tbase + m;
        c[m] = (idx < n) ? v[idx] : 0;
        tot += c[m];
    }
    lds[tid] = tot;
    __syncthreads();
    for (int o = 1; o < 256; o <<= 1) {
        int val = (tid >= o) ? lds[tid - o] : 0;
        __syncthreads();
        lds[tid] += val;
        __syncthreads();
    }
    int run = part[blockIdx.x] + lds[tid] - tot;
#pragma unroll
    for (int m = 0; m < 8; ++m) {
        int idx = tbase + m;
        if (idx < n) off[idx] = run;
        run += c[m];
    }
    if (blockIdx.x == 0 && tid == 0) off[n] = total;
}

// ---------------- Pass 3: bin packed edges into tile regions ----------------
__global__ __launch_bounds__(1024) void k_binfill(
    const int* __restrict__ src, const int* __restrict__ dst,
    const int* __restrict__ off, unsigned int* __restrict__ ebuf,
    int n_edges, int NB, int C)
{
    __shared__ int lcur[MAX_NB];
    const int c = blockIdx.x;
    for (int b = threadIdx.x; b < NB; b += 1024)
        lcur[b] = off[b * C + c];
    __syncthreads();
    const int beg = c * CE;
    const int end = min(beg + CE, n_edges);
    for (int e = beg + threadIdx.x; e < end; e += 1024) {
        const int d = dst[e];
        const int b = d >> 8;
        const unsigned int dl = (unsigned int)(d & 255);
        const int pos = atomicAdd(&lcur[b], 1);
        ebuf[pos] = (dl << 17) | (unsigned int)src[e];
    }
}

// ---------------- Pass 4: per-tile counting sort -> eidx + ptr ----------------
__global__ __launch_bounds__(1024) void k_tile_sort(
    const int* __restrict__ off, const unsigned int* __restrict__ ebuf,
    int* __restrict__ eidx, int* __restrict__ ptr,
    int n_nodes, int NB, int C, int n_edges)
{
    __shared__ int hist[TILE_NODES];
    __shared__ int scan[TILE_NODES];
    __shared__ int cur[TILE_NODES];
    const int t = blockIdx.x;
    const int beg = off[t * C];
    const int end = (t + 1 < NB) ? off[(t + 1) * C] : n_edges;
    const int node_base = t * TILE_NODES;
    const int n_valid = min(TILE_NODES, n_nodes - node_base);

    if (threadIdx.x < TILE_NODES) hist[threadIdx.x] = 0;
    __syncthreads();
    for (int e = beg + threadIdx.x; e < end; e += 1024)
        atomicAdd(&hist[ebuf[e] >> 17], 1);
    __syncthreads();
    if (threadIdx.x < TILE_NODES) scan[threadIdx.x] = hist[threadIdx.x];
    __syncthreads();
    for (int o = 1; o < TILE_NODES; o <<= 1) {
        int v = 0;
        if (threadIdx.x < TILE_NODES && threadIdx.x >= o) v = scan[threadIdx.x - o];
        __syncthreads();
        if (threadIdx.x < TILE_NODES) scan[threadIdx.x] += v;
        __syncthreads();
    }
    if (threadIdx.x < TILE_NODES) {
        const int ex = scan[threadIdx.x] - hist[threadIdx.x];   // exclusive
        cur[threadIdx.x] = ex;
        if (threadIdx.x < n_valid) ptr[node_base + threadIdx.x] = beg + ex;
    }
    if (t == NB - 1 && threadIdx.x == 0) ptr[n_nodes] = n_edges;
    __syncthreads();
    for (int e = beg + threadIdx.x; e < end; e += 1024) {
        const unsigned int v = ebuf[e];
        const int dl = (int)(v >> 17);
        const int pos = beg + atomicAdd(&cur[dl], 1);
        eidx[pos] = (int)(v & 0x1FFFFu);
    }
}

// ---------------- Layer 0: A(bf16) = x@Wn0 ; B = x@Ws0 + bn0 ----------------
__global__ __launch_bounds__(256) void k_layer0(
    const float* __restrict__ x, const float* __restrict__ Wn0,
    const float* __restrict__ bn0, const float* __restrict__ Ws0,
    ushort* __restrict__ Ab, float* __restrict__ B, int n_nodes)
{
    __shared__ float sWn[128 * 32];
    __shared__ float sWs[128 * 32];
    __shared__ float sx[32 * 128];

    for (int i = threadIdx.x; i < 128 * 32; i += 256) {
        sWn[i] = Wn0[i];
        sWs[i] = Ws0[i];
    }
    const int tile = blockIdx.x * 32;
    {
        const float4* s4 = (const float4*)(x + (size_t)tile * 128);
        const int lim = (n_nodes - tile) * 32;
#pragma unroll
        for (int m = 0; m < 4; ++m) {
            int i = threadIdx.x + m * 256;
            if (i < lim) ((float4*)sx)[i] = s4[i];
        }
    }
    const int j = threadIdx.x & 31;
    const int r = threadIdx.x >> 5;
    const float bias = bn0[j];
    __syncthreads();

    float accA[4] = {0.f, 0.f, 0.f, 0.f};
    float accB[4] = {bias, bias, bias, bias};
#pragma unroll 8
    for (int k = 0; k < 128; ++k) {
        const float wn = sWn[k * 32 + j];
        const float ws = sWs[k * 32 + j];
#pragma unroll
        for (int m = 0; m < 4; ++m) {
            const float xv = sx[(r + 8 * m) * 128 + k];
            accA[m] += xv * wn;
            accB[m] += xv * ws;
        }
    }
#pragma unroll
    for (int m = 0; m < 4; ++m) {
        const int node = tile + r + 8 * m;
        if (node < n_nodes) {
            Ab[(size_t)node * 32 + j] = f2bf(accA[m]);
            B[(size_t)node * 32 + j] = accB[m];
        }
    }
}

// ------------- Layers 1..3 (in-place on B): A(bf16) = relu(B)@Wn ; B = relu(B)@Ws + bn -------------
__global__ __launch_bounds__(256) void k_layer(
    float* HB,                       // read pre-act, overwritten with new B
    const float* __restrict__ Wn, const float* __restrict__ bnv,
    const float* __restrict__ Ws, ushort* __restrict__ Ab, int n_nodes)
{
    __shared__ float sWn[32 * 32];
    __shared__ float sWs[32 * 32];
    __shared__ float sh[64 * 32];

    for (int i = threadIdx.x; i < 1024; i += 256) {
        sWn[i] = Wn[i];
        sWs[i] = Ws[i];
    }
    const int tile = blockIdx.x * 64;
    {
        const float4* s4 = (const float4*)(HB + (size_t)tile * 32);
        const int lim = (n_nodes - tile) * 8;
#pragma unroll
        for (int m = 0; m < 2; ++m) {
            int i = threadIdx.x + m * 256;
            if (i < lim) {
                float4 v = s4[i];
                v.x = fmaxf(v.x, 0.f); v.y = fmaxf(v.y, 0.f);
                v.z = fmaxf(v.z, 0.f); v.w = fmaxf(v.w, 0.f);
                ((float4*)sh)[i] = v;
            }
        }
    }
    const int j = threadIdx.x & 31;
    const int r = threadIdx.x >> 5;
    const float bias = bnv[j];
    __syncthreads();

    float accA[8] = {0.f};
    float accB[8];
#pragma unroll
    for (int m = 0; m < 8; ++m) accB[m] = bias;
#pragma unroll
    for (int k = 0; k < 32; ++k) {
        const float wn = sWn[k * 32 + j];
        const float ws = sWs[k * 32 + j];
#pragma unroll
        for (int m = 0; m < 8; ++m) {
            const float hv = sh[(r + 8 * m) * 32 + k];
            accA[m] += hv * wn;
            accB[m] += hv * ws;
        }
    }
#pragma unroll
    for (int m = 0; m < 8; ++m) {
        const int node = tile + r + 8 * m;
        if (node < n_nodes) {
            Ab[(size_t)node * 32 + j] = f2bf(accA[m]);
            HB[(size_t)node * 32 + j] = accB[m];
        }
    }
}

// ------------- Aggregation: B[n] += sum_{e in CSR[n]} A_bf16[eidx[e]] -------------
// 4 lanes per node (uint4 = 8 bf16 each, 64B row), 8-edge unrolled batches.
__global__ __launch_bounds__(256) void k_agg2(
    const int* __restrict__ ptr, const int* __restrict__ eidx,
    const ushort* __restrict__ Ab, float* __restrict__ B, int n_nodes)
{
    const int g    = blockIdx.x * 64 + (threadIdx.x >> 2);
    const int lane = threadIdx.x & 3;
    if (g >= n_nodes) return;
    const int beg = ptr[g];
    const int end = ptr[g + 1];
    const uint4* __restrict__ A4 = (const uint4*)Ab;   // 16B = 8 bf16
    float4* B4 = (float4*)B;

    float4 acc0 = B4[(size_t)g * 8 + lane * 2];       // cols 8l..8l+3
    float4 acc1 = B4[(size_t)g * 8 + lane * 2 + 1];   // cols 8l+4..8l+7
    for (int e = beg; e < end; e += 8) {
        int idx[8];
#pragma unroll
        for (int u = 0; u < 8; ++u)
            idx[u] = (e + u < end) ? eidx[e + u] : -1;
#pragma unroll
        for (int u = 0; u < 8; ++u) {
            if (idx[u] >= 0) {
                const uint4 rw = A4[(size_t)idx[u] * 4 + lane];
                acc0.x += bf_lo(rw.x); acc0.y += bf_hi(rw.x);
                acc0.z += bf_lo(rw.y); acc0.w += bf_hi(rw.y);
                acc1.x += bf_lo(rw.z); acc1.y += bf_hi(rw.z);
                acc1.z += bf_lo(rw.w); acc1.w += bf_hi(rw.w);
            }
        }
    }
    B4[(size_t)g * 8 + lane * 2]     = acc0;
    B4[(size_t)g * 8 + lane * 2 + 1] = acc1;
}

// ---------------- Zero hg ----------------
__global__ __launch_bounds__(256) void k_zero_f(float* __restrict__ p, int n)
{
    int i = blockIdx.x * 256 + threadIdx.x;
    if (i < n) p[i] = 0.f;
}

// ---------------- Node-parallel per-graph sum pool ----------------
__global__ __launch_bounds__(256) void k_pool1(
    const float* __restrict__ H, const int* __restrict__ gids,
    float* __restrict__ hg, int n_nodes)
{
    const int base = blockIdx.x * 128;
    const int lim  = min(base + 128, n_nodes);
    const int j = threadIdx.x & 31;
    const int r = threadIdx.x >> 5;

    int curg = -1;
    float acc = 0.f;
    for (int n = base + r; n < lim; n += 8) {
        const int g = gids[n];
        const float v = fmaxf(H[(size_t)n * 32 + j], 0.f);
        if (g != curg) {
            if (curg >= 0) atomicAdd(&hg[curg * 32 + j], acc);
            curg = g;
            acc = v;
        } else {
            acc += v;
        }
    }
    if (curg >= 0) atomicAdd(&hg[curg * 32 + j], acc);
}

// ---------------- FC head + softmax ----------------
__global__ __launch_bounds__(64) void k_head(
    const float* __restrict__ hg,
    const float* __restrict__ Wfc1, const float* __restrict__ bfc1,
    const float* __restrict__ Wout, const float* __restrict__ bout,
    float* __restrict__ out, int n_graphs)
{
    const int g = blockIdx.x * blockDim.x + threadIdx.x;
    if (g >= n_graphs) return;
    float h[32];
#pragma unroll
    for (int k = 0; k < 32; ++k) h[k] = hg[g * 32 + k];
    float z[8];
#pragma unroll
    for (int m = 0; m < 8; ++m) {
        float a = bfc1[m];
#pragma unroll
        for (int k = 0; k < 32; ++k) a += h[k] * Wfc1[k * 8 + m];
        z[m] = fmaxf(a, 0.f);
    }
    float o[4];
#pragma unroll
    for (int q = 0; q < 4; ++q) {
        float a = bout[q];
#pragma unroll
        for (int m = 0; m < 8; ++m) a += z[m] * Wout[m * 4 + q];
        o[q] = fmaxf(a, 0.f);
    }
    const float mx = fmaxf(fmaxf(o[0], o[1]), fmaxf(o[2], o[3]));
    const float e0 = expf(o[0] - mx), e1 = expf(o[1] - mx);
    const float e2 = expf(o[2] - mx), e3 = expf(o[3] - mx);
    const float inv = 1.f / (e0 + e1 + e2 + e3);
    out[g * 4 + 0] = e0 * inv;
    out[g * 4 + 1] = e1 * inv;
    out[g * 4 + 2] = e2 * inv;
    out[g * 4 + 3] = e3 * inv;
}

extern "C" void kernel_launch(void* const* d_in, const int* in_sizes, int n_in,
                              void* d_out, int out_size, void* d_ws, size_t ws_size,
                              hipStream_t stream)
{
    const float* x    = (const float*)d_in[0];
    const float* Wn0  = (const float*)d_in[1];
    const float* bn0  = (const float*)d_in[2];
    const float* Ws0  = (const float*)d_in[3];
    const float* Wn   = (const float*)d_in[4];   // [3,32,32]
    const float* bn   = (const float*)d_in[5];   // [3,32]
    const float* Ws   = (const float*)d_in[6];   // [3,32,32]
    const float* Wfc1 = (const float*)d_in[7];
    const float* bfc1 = (const float*)d_in[8];
    const float* Wout = (const float*)d_in[9];
    const float* bout = (const float*)d_in[10];
    const int*   src  = (const int*)d_in[11];
    const int*   dst  = (const int*)d_in[12];
    const int*   gids = (const int*)d_in[13];

    const int n_nodes  = in_sizes[0] / 128;
    const int n_edges  = in_sizes[11];
    const int n_graphs = out_size / 4;
    const size_t N32 = (size_t)n_nodes * 32;

    const int NB = (n_nodes + TILE_NODES - 1) / TILE_NODES;
    const int C  = (n_edges + CE - 1) / CE;
    const int n_off = NB * C;

    ushort* Ab = (ushort*)d_ws;                          // [N,32] bf16
    float* B   = (float*)(Ab + N32);                     // [N,32] fp32 (in-place)
    float* hg  = B + N32;                                // [G,32]
    int* histT = (int*)(hg + (size_t)n_graphs * 32);     // [NB*C]
    int* off   = histT + n_off;                          // [NB*C + 1]
    int* part  = off + n_off + 1;                        // [<=256]
    int* ptr   = part + 256;                             // [N+1]
    unsigned int* ebuf = (unsigned int*)(ptr + n_nodes + 1);  // [E]
    int* eidx  = (int*)(ebuf + n_edges);                 // [E]

    const int nparts = (n_off + SCAN_CHUNK - 1) / SCAN_CHUNK;

    // ---- edge sort (once per call; reused by all 4 layers) ----
    k_hist2<<<C, 1024, 0, stream>>>(dst, histT, n_edges, NB, C);
    k_chunk_sum<<<nparts, 256, 0, stream>>>(histT, part, n_off);
    k_scan_part<<<1, 64, 0, stream>>>(part, nparts);
    k_write_off<<<nparts, 256, 0, stream>>>(histT, part, off, n_off, n_edges);
    k_binfill<<<C, 1024, 0, stream>>>(src, dst, off, ebuf, n_edges, NB, C);
    k_tile_sort<<<NB, 1024, 0, stream>>>(off, ebuf, eidx, ptr, n_nodes, NB, C, n_edges);

    const int mblocks0 = (n_nodes + 31) / 32;
    const int mblocks  = (n_nodes + 63) / 64;
    const int ablocks  = (n_nodes + 63) / 64;

    // ---- Layer 0 ----
    k_layer0<<<mblocks0, 256, 0, stream>>>(x, Wn0, bn0, Ws0, Ab, B, n_nodes);
    k_agg2<<<ablocks, 256, 0, stream>>>(ptr, eidx, Ab, B, n_nodes);

    // ---- Layers 1..3 (in-place on B) ----
    for (int l = 0; l < 3; ++l) {
        k_layer<<<mblocks, 256, 0, stream>>>(B, Wn + l * 1024, bn + l * 32,
                                             Ws + l * 1024, Ab, n_nodes);
        k_agg2<<<ablocks, 256, 0, stream>>>(ptr, eidx, Ab, B, n_nodes);
    }

    // ---- Pool + head ----
    k_zero_f<<<(n_graphs * 32 + 255) / 256, 256, 0, stream>>>(hg, n_graphs * 32);
    k_pool1<<<(n_nodes + 127) / 128, 256, 0, stream>>>(B, gids, hg, n_nodes);
    k_head<<<(n_graphs + 63) / 64, 64, 0, stream>>>(hg, Wfc1, bfc1, Wout, bout,
                                                    (float*)d_out, n_graphs);
}